// Round 5
// baseline (866.715 us; speedup 1.0000x reference)
//
#include <hip/hip_runtime.h>

typedef __bf16 bf16x8 __attribute__((ext_vector_type(8)));
typedef float f32x4 __attribute__((ext_vector_type(4)));
typedef unsigned short u16x4 __attribute__((ext_vector_type(4)));
typedef unsigned short u16x8 __attribute__((ext_vector_type(8)));

#define MFMA16(a,b,c) __builtin_amdgcn_mfma_f32_16x16x32_bf16((a),(b),(c),0,0,0)

__device__ __forceinline__ unsigned short f2bf(float f){
  return __builtin_bit_cast(unsigned short, static_cast<__bf16>(f));
}
__device__ __forceinline__ float bf2f(unsigned short h){
  unsigned u = ((unsigned)h)<<16;
  return __builtin_bit_cast(float, u);
}
__device__ __forceinline__ bf16x8 g_frag(const unsigned short* __restrict__ wf, int fragIdx, int lane){
  return __builtin_bit_cast(bf16x8, *reinterpret_cast<const u16x8*>(wf + (size_t)(fragIdx*64 + lane)*8));
}
__device__ __forceinline__ bf16x8 lds_frag(const unsigned short* base, int fragIdx, int lane){
  return __builtin_bit_cast(bf16x8, *reinterpret_cast<const u16x8*>(base + (fragIdx*64 + lane)*8));
}
__device__ __forceinline__ bf16x8 bc(u16x8 v){ return __builtin_bit_cast(bf16x8, v); }

// Pack W^T (from W[K][M] f32 row-major) into MFMA fragment order, bf16:
// dst[((mt*KP+kp)*64+lane)*8 + j] = W[4*(lane>>4)+(j&3)+16*(j>>2)+32*kp][16*mt+(lane&15)]
// Serves as A-frag (m = row dim) or B-frag (m = col dim) -- same position map.
__device__ __forceinline__ void pack_body(const float* __restrict__ src, unsigned short* __restrict__ dst,
                                          int blk, int MT, int KP, int M){
  int tid = blk*256 + threadIdx.x;
  if (tid >= MT*KP*64) return;
  int lane = tid & 63;
  int t2 = tid >> 6;
  int kp = t2 % KP;
  int m = 16*(t2 / KP) + (lane & 15);
  int g = lane >> 4;
  u16x8 v;
#pragma unroll
  for (int j = 0; j < 8; ++j) {
    int k = 4*g + (j&3) + 16*(j>>2) + 32*kp;
    v[j] = f2bf(src[k*M + m]);
  }
  *reinterpret_cast<u16x8*>(&dst[(size_t)tid*8]) = v;
}

// One fused prep kernel: all weight packing + bias2 table. Grid = 160 blocks.
// bias2[(((h*4+mt)*4+nt)*64+lane)*4 + r2] = bias[h][key=16mt+4g+r2][q=16nt+l15]
// (replicates np.meshgrid 'xy': d/h coordinate roles swapped -- intentional)
__global__ void prep_kernel(const float* __restrict__ qkvw, const float* __restrict__ pw,
                            const float* __restrict__ w1, const float* __restrict__ w2,
                            const float* __restrict__ tbl,
                            unsigned short* __restrict__ wqk_f, unsigned short* __restrict__ wvb_f,
                            unsigned short* __restrict__ wproj_f,
                            unsigned short* __restrict__ w1_f, unsigned short* __restrict__ w2_f,
                            float* __restrict__ bias2){
  const int bb = blockIdx.x;
  if (bb < 16)      { pack_body(qkvw,       wqk_f,   bb,      16, 4, 384); return; }
  else if (bb < 24) { pack_body(qkvw + 256, wvb_f,   bb-16,    8, 4, 384); return; }
  else if (bb < 32) { pack_body(pw,         wproj_f, bb-24,    8, 4, 128); return; }
  else if (bb < 64) { pack_body(w1,         w1_f,    bb-32,   32, 4, 512); return; }
  else if (bb < 96) { pack_body(w2,         w2_f,    bb-64,    8,16, 128); return; }
  const int o = (bb-96)*256 + threadIdx.x;   // 64 blocks -> 16384 items
  int r2 = o&3, lane = (o>>2)&63, nt = (o>>8)&3, mt = (o>>10)&3, h = o>>12;
  int g = lane>>4, l15 = lane&15;
  int key = 16*mt + 4*g + r2, q = 16*nt + l15;
  int da = ((q>>2)&3) - ((key>>2)&3) + 3;
  int ha = (q>>4)     - (key>>4)     + 3;
  int wa = (q&3)      - (key&3)      + 3;
  bias2[o] = tbl[((da*7+ha)*7+wa)*4 + h];
}

__global__ __launch_bounds__(256, 2)
void swin_block_kernel(const float* __restrict__ x,
                       const float* __restrict__ n1s, const float* __restrict__ n1b,
                       const unsigned short* __restrict__ wqk,
                       const unsigned short* __restrict__ wvb,
                       const float* __restrict__ bias2,
                       const unsigned short* __restrict__ wproj,
                       const float* __restrict__ projb,
                       const float* __restrict__ n2s, const float* __restrict__ n2b,
                       const unsigned short* __restrict__ w1f, const float* __restrict__ b1,
                       const unsigned short* __restrict__ w2f, const float* __restrict__ b2,
                       float* __restrict__ out)
{
  // Two fragment-packed arenas; frag f = tile*4+kp = 64 lanes x 16B. All b128, conflict-free.
  __shared__ __align__(16) unsigned short ldsA[16*64*8];  // xn -> o -> xn2
  __shared__ __align__(16) unsigned short ldsH[16*64*8];  // proj-stage -> mlp-stage
  __shared__ int rid_s[64];

  const int tid  = threadIdx.x;
  const int lane = tid & 63;
  const int w    = tid >> 6;      // wave id = head id = token-tile id (phase-dependent role)
  const int g    = lane >> 4;
  const int l15  = lane & 15;

  const int wb = blockIdx.x;
  const int b  = wb >> 11;
  const int r0 = wb & 2047;
  const int bd = r0 >> 8, bh = (r0 >> 4) & 15, bwi = r0 & 15;
  const bool edge = (bd==7) || (bh==15) || (bwi==15);

  // ---- phase 0: load x (roll -2 fused), LN1 -> xn frags; residual -> bf16 regs ----
  const int t = tid >> 2, qtr = tid & 3;
  const int wd = t >> 4, wh = (t >> 2) & 3, ww = t & 3;
  const int dco = (bd*4 + wd + 2) & 31;
  const int hco = (bh*4 + wh + 2) & 63;
  const int wco = (bwi*4 + ww + 2) & 63;
  const long tokl = ((long)((b*32 + dco)*64 + hco))*64 + wco;
  const float* xrow = x + tokl*128 + qtr*32;
  const int tileT = t >> 4, l15t = t & 15;

  u16x8 rsd[4];
  {
    float xr[32];
    float s = 0.f, sq = 0.f;
#pragma unroll
    for (int i = 0; i < 8; ++i) {
      float4 v = reinterpret_cast<const float4*>(xrow)[i];
      xr[4*i+0]=v.x; xr[4*i+1]=v.y; xr[4*i+2]=v.z; xr[4*i+3]=v.w;
      s  += v.x + v.y + v.z + v.w;
      sq += v.x*v.x + v.y*v.y + v.z*v.z + v.w*v.w;
    }
    s  += __shfl_xor(s, 1);  s  += __shfl_xor(s, 2);
    sq += __shfl_xor(sq, 1); sq += __shfl_xor(sq, 2);
    const float mean = s * 0.0078125f;
    const float rs   = rsqrtf(sq * 0.0078125f - mean*mean + 1e-6f);
#pragma unroll
    for (int i = 0; i < 8; ++i) {
      u16x4 o4;
#pragma unroll
      for (int j2 = 0; j2 < 4; ++j2) {
        int c = qtr*32 + 4*i + j2;
        o4[j2] = f2bf((xr[4*i+j2]-mean)*rs*n1s[c] + n1b[c]);
        rsd[i>>1][4*(i&1)+j2] = f2bf(xr[4*i+j2]);
      }
      *reinterpret_cast<u16x4*>(&ldsA[((tileT*4+qtr)*64 + l15t + 16*(i&3))*8 + 4*(i>>2)]) = o4;
    }
  }
  if (edge && tid < 64) {
    int twd = tid >> 4, twh = (tid >> 2) & 3, tww = tid & 3;
    int rd = (bd == 7)  ? (twd < 2 ? 1 : 2) : 0;
    int rh = (bh == 15) ? (twh < 2 ? 1 : 2) : 0;
    int rw = (bwi == 15)? (tww < 2 ? 1 : 2) : 0;
    rid_s[tid] = rd*9 + rh*3 + rw;
  }
  __syncthreads();   // B0: xn ready

  // ---- phase 1: QKV (wave = head); Q,K,V share the same xn frags per kp ----
  u16x8 Qf[4], Kf[4], Vf[2][2];
  {
    f32x4 qacc[2][4], kacc[2][4], vacc[4][2];
#pragma unroll
    for (int a2=0;a2<2;++a2)
#pragma unroll
      for (int b4=0;b4<4;++b4){ f32x4 z={0.f,0.f,0.f,0.f}; qacc[a2][b4]=z; kacc[a2][b4]=z; vacc[b4][a2]=z; }
#pragma unroll
    for (int kp=0;kp<4;++kp){
      bf16x8 fx[4];
#pragma unroll
      for (int nt=0;nt<4;++nt) fx[nt] = lds_frag(ldsA, nt*4+kp, lane);
#pragma unroll
      for (int mi=0;mi<2;++mi){
        bf16x8 aq = g_frag(wqk, (2*w+mi)*4+kp, lane);
#pragma unroll
        for (int nt=0;nt<4;++nt) qacc[mi][nt] = MFMA16(aq, fx[nt], qacc[mi][nt]);
      }
#pragma unroll
      for (int mi=0;mi<2;++mi){
        bf16x8 ak = g_frag(wqk, (8+2*w+mi)*4+kp, lane);
#pragma unroll
        for (int nt=0;nt<4;++nt) kacc[mi][nt] = MFMA16(ak, fx[nt], kacc[mi][nt]);
      }
#pragma unroll
      for (int c2=0;c2<2;++c2){
        bf16x8 bv = g_frag(wvb, (2*w+c2)*4+kp, lane);
#pragma unroll
        for (int mt=0;mt<4;++mt) vacc[mt][c2] = MFMA16(fx[mt], bv, vacc[mt][c2]);
      }
    }
#pragma unroll
    for (int nt=0;nt<4;++nt){
      u16x8 vq, vk;
#pragma unroll
      for (int j=0;j<8;++j){
        vq[j] = f2bf(qacc[j>>2][nt][j&3]*0.17677669529663687f);
        vk[j] = f2bf(kacc[j>>2][nt][j&3]);
      }
      Qf[nt]=vq; Kf[nt]=vk;
    }
#pragma unroll
    for (int c2=0;c2<2;++c2)
#pragma unroll
      for (int kpk=0;kpk<2;++kpk){
        u16x8 v;
#pragma unroll
        for (int j=0;j<8;++j) v[j] = f2bf(vacc[(j>>2)+2*kpk][c2][j&3]);
        Vf[c2][kpk]=v;
      }
  }
  __syncthreads();   // B1: all xn reads done (o will overwrite arena A)

  // ---- phase 2: attention in registers, streamed per q-tile ----
  {
    int4 rk[4];
    if (edge){
#pragma unroll
      for (int mt=0;mt<4;++mt) rk[mt] = *reinterpret_cast<const int4*>(&rid_s[16*mt + 4*g]);
    }
#pragma unroll
    for (int nt=0;nt<4;++nt){
      f32x4 sacc[4];
#pragma unroll
      for (int mt=0;mt<4;++mt){
        f32x4 z = {0.f,0.f,0.f,0.f};
        sacc[mt] = MFMA16(bc(Kf[mt]), bc(Qf[nt]), z);
      }
      if (edge){
        const int ridq = rid_s[16*nt + l15];
#pragma unroll
        for (int mt=0;mt<4;++mt){
          float4 bv = reinterpret_cast<const float4*>(bias2)[((w*4+mt)*4+nt)*64 + lane];
          sacc[mt][0] += bv.x + (rk[mt].x != ridq ? -100.f : 0.f);
          sacc[mt][1] += bv.y + (rk[mt].y != ridq ? -100.f : 0.f);
          sacc[mt][2] += bv.z + (rk[mt].z != ridq ? -100.f : 0.f);
          sacc[mt][3] += bv.w + (rk[mt].w != ridq ? -100.f : 0.f);
        }
      } else {
#pragma unroll
        for (int mt=0;mt<4;++mt){
          float4 bv = reinterpret_cast<const float4*>(bias2)[((w*4+mt)*4+nt)*64 + lane];
          sacc[mt][0] += bv.x; sacc[mt][1] += bv.y; sacc[mt][2] += bv.z; sacc[mt][3] += bv.w;
        }
      }
      float mx = -1e30f;
#pragma unroll
      for (int mt=0;mt<4;++mt)
#pragma unroll
        for (int r2=0;r2<4;++r2) mx = fmaxf(mx, sacc[mt][r2]);
      mx = fmaxf(mx, __shfl_xor(mx, 16));
      mx = fmaxf(mx, __shfl_xor(mx, 32));
      float sum = 0.f;
#pragma unroll
      for (int mt=0;mt<4;++mt)
#pragma unroll
        for (int r2=0;r2<4;++r2){
          float p = __expf(sacc[mt][r2] - mx);
          sacc[mt][r2] = p; sum += p;
        }
      sum += __shfl_xor(sum, 16);
      sum += __shfl_xor(sum, 32);
      const float inv = 1.f / sum;
      u16x8 Pf0, Pf1;
#pragma unroll
      for (int j=0;j<8;++j){
        Pf0[j] = f2bf(sacc[(j>>2)  ][j&3]*inv);
        Pf1[j] = f2bf(sacc[(j>>2)+2][j&3]*inv);
      }
      f32x4 oa[2];
#pragma unroll
      for (int c2=0;c2<2;++c2){
        f32x4 z = {0.f,0.f,0.f,0.f};
        z = MFMA16(bc(Vf[c2][0]), bc(Pf0), z);
        oa[c2] = MFMA16(bc(Vf[c2][1]), bc(Pf1), z);
      }
      u16x8 v;
#pragma unroll
      for (int j=0;j<8;++j) v[j] = f2bf(oa[j>>2][j&3]);
      *reinterpret_cast<u16x8*>(&ldsA[((nt*4+w)*64+lane)*8]) = v;   // frag (tok-tile nt, kp=head w)
    }
  }
  __syncthreads();   // B2: o ready

  // ---- phase 3: proj (wave = token tile w), stage -> ldsH ----
  {
    f32x4 pacc[8];
#pragma unroll
    for (int mt=0;mt<8;++mt){ f32x4 z={0.f,0.f,0.f,0.f}; pacc[mt]=z; }
#pragma unroll
    for (int kp=0;kp<4;++kp){
      bf16x8 bo = lds_frag(ldsA, w*4+kp, lane);
#pragma unroll
      for (int mt=0;mt<8;++mt)
        pacc[mt] = MFMA16(g_frag(wproj, mt*4+kp, lane), bo, pacc[mt]);
    }
#pragma unroll
    for (int mt=0;mt<8;++mt){
      float4 pb = *reinterpret_cast<const float4*>(&projb[16*mt + 4*g]);
      pacc[mt][0]+=pb.x; pacc[mt][1]+=pb.y; pacc[mt][2]+=pb.z; pacc[mt][3]+=pb.w;
    }
#pragma unroll
    for (int q2=0;q2<4;++q2){
      u16x8 v;
#pragma unroll
      for (int j=0;j<8;++j) v[j] = f2bf(pacc[2*q2+(j>>2)][j&3]);
      *reinterpret_cast<u16x8*>(&ldsH[((w*4+q2)*64+lane)*8]) = v;
    }
  }
  __syncthreads();   // B3: proj stage ready; ldsA o-reads done

  // ---- phase 4: residual + LN2 (reads ldsH) -> xn2 frags in ldsA; resid2 -> regs ----
  {
    float xv[32];
    float s2 = 0.f, sq2 = 0.f;
#pragma unroll
    for (int i = 0; i < 8; ++i) {
      u16x4 sg = *reinterpret_cast<const u16x4*>(&ldsH[((tileT*4+qtr)*64 + l15t + 16*(i&3))*8 + 4*(i>>2)]);
#pragma unroll
      for (int j2 = 0; j2 < 4; ++j2) {
        float v2 = bf2f(rsd[i>>1][4*(i&1)+j2]) + bf2f(sg[j2]);
        xv[4*i+j2] = v2;
        s2 += v2; sq2 += v2*v2;
      }
    }
    s2  += __shfl_xor(s2, 1);  s2  += __shfl_xor(s2, 2);
    sq2 += __shfl_xor(sq2, 1); sq2 += __shfl_xor(sq2, 2);
    const float mean2 = s2*0.0078125f;
    const float rs2 = rsqrtf(sq2*0.0078125f - mean2*mean2 + 1e-6f);
#pragma unroll
    for (int i = 0; i < 8; ++i) {
      u16x4 o4;
#pragma unroll
      for (int j2 = 0; j2 < 4; ++j2) {
        int c = qtr*32 + 4*i + j2;
        o4[j2] = f2bf((xv[4*i+j2]-mean2)*rs2*n2s[c] + n2b[c]);
        rsd[i>>1][4*(i&1)+j2] = f2bf(xv[4*i+j2]);
      }
      *reinterpret_cast<u16x4*>(&ldsA[((tileT*4+qtr)*64 + l15t + 16*(i&3))*8 + 4*(i>>2)]) = o4;
    }
  }
  __syncthreads();   // B5: xn2 ready (ldsH reads done)

  // ---- phase 5: MLP (wave = token tile w), hidden entirely in registers ----
  {
    bf16x8 Bn[4];
#pragma unroll
    for (int kp=0;kp<4;++kp) Bn[kp] = lds_frag(ldsA, w*4+kp, lane);
    f32x4 macc[8];
#pragma unroll
    for (int mt=0;mt<8;++mt){ f32x4 z={0.f,0.f,0.f,0.f}; macc[mt]=z; }
#pragma unroll 4
    for (int kp2=0;kp2<16;++kp2){
      f32x4 hacc[2];
#pragma unroll
      for (int hi=0;hi<2;++hi){
        f32x4 z = {0.f,0.f,0.f,0.f};
#pragma unroll
        for (int kp1=0;kp1<4;++kp1)
          z = MFMA16(g_frag(w1f, (2*kp2+hi)*4+kp1, lane), Bn[kp1], z);
        hacc[hi] = z;
      }
      u16x8 bhv;
#pragma unroll
      for (int hi=0;hi<2;++hi){
        float4 bb = *reinterpret_cast<const float4*>(&b1[32*kp2 + 16*hi + 4*g]);
#pragma unroll
        for (int r2=0;r2<4;++r2){
          float v2 = hacc[hi][r2] + (&bb.x)[r2];
          float gg = 0.7978845608028654f*(v2 + 0.044715f*v2*v2*v2);
          float ge = v2 / (1.f + __expf(-2.f*gg));   // 0.5 v (1+tanh(gg))
          bhv[4*hi+r2] = f2bf(ge);
        }
      }
#pragma unroll
      for (int mt=0;mt<8;++mt)
        macc[mt] = MFMA16(g_frag(w2f, mt*16+kp2, lane), bc(bhv), macc[mt]);
    }
    // stage mlp out (+b2) -> ldsH
#pragma unroll
    for (int q2=0;q2<4;++q2){
      u16x8 v;
#pragma unroll
      for (int j=0;j<8;++j){
        const int mt = 2*q2+(j>>2);
        v[j] = f2bf(macc[mt][j&3] + b2[16*mt + 4*g + (j&3)]);
      }
      *reinterpret_cast<u16x8*>(&ldsH[((w*4+q2)*64+lane)*8]) = v;
    }
  }
  __syncthreads();   // B6: mlp stage ready

  // ---- phase 6: out = resid2 + mlp (coalesced float4 stores) ----
  {
    float* orow = out + tokl*128 + qtr*32;
#pragma unroll
    for (int i = 0; i < 8; ++i) {
      u16x4 mv = *reinterpret_cast<const u16x4*>(&ldsH[((tileT*4+qtr)*64 + l15t + 16*(i&3))*8 + 4*(i>>2)]);
      float4 v;
      v.x = bf2f(rsd[i>>1][4*(i&1)+0]) + bf2f(mv[0]);
      v.y = bf2f(rsd[i>>1][4*(i&1)+1]) + bf2f(mv[1]);
      v.z = bf2f(rsd[i>>1][4*(i&1)+2]) + bf2f(mv[2]);
      v.w = bf2f(rsd[i>>1][4*(i&1)+3]) + bf2f(mv[3]);
      reinterpret_cast<float4*>(orow)[i] = v;
    }
  }
}

extern "C" void kernel_launch(void* const* d_in, const int* in_sizes, int n_in,
                              void* d_out, int out_size, void* d_ws, size_t ws_size,
                              hipStream_t stream) {
  (void)in_sizes; (void)n_in; (void)out_size; (void)ws_size;
  const float* x    = (const float*)d_in[0];
  // d_in[1] (mask) recomputed analytically in-kernel
  const float* n1s  = (const float*)d_in[2];
  const float* n1b  = (const float*)d_in[3];
  const float* qkvw = (const float*)d_in[4];
  const float* tbl  = (const float*)d_in[5];
  const float* pw   = (const float*)d_in[6];
  const float* pb   = (const float*)d_in[7];
  const float* n2s  = (const float*)d_in[8];
  const float* n2b  = (const float*)d_in[9];
  const float* w1   = (const float*)d_in[10];
  const float* b1   = (const float*)d_in[11];
  const float* w2   = (const float*)d_in[12];
  const float* b2   = (const float*)d_in[13];
  float* out = (float*)d_out;

  // ws layout (u16 units): wqk 16*4*64*8 | wvb 8*4*64*8 | wproj 8*4*64*8 | w1 32*4*64*8 | w2 8*16*64*8 | bias2 f32 16384
  unsigned short* wqk_f   = (unsigned short*)d_ws;
  unsigned short* wvb_f   = wqk_f   + 16*4*64*8;
  unsigned short* wproj_f = wvb_f   + 8*4*64*8;
  unsigned short* w1_f    = wproj_f + 8*4*64*8;
  unsigned short* w2_f    = w1_f    + 32*4*64*8;
  float*          bias2   = (float*)(w2_f + 8*16*64*8);

  prep_kernel<<<160, 256, 0, stream>>>(qkvw, pw, w1, w2, tbl,
                                       wqk_f, wvb_f, wproj_f, w1_f, w2_f, bias2);

  swin_block_kernel<<<4096, 256, 0, stream>>>(x, n1s, n1b, wqk_f, wvb_f, bias2, wproj_f, pb,
                                              n2s, n2b, w1_f, b1, w2_f, b2, out);
}

// Round 6
// 552.089 us; speedup vs baseline: 1.5699x; 1.5699x over previous
//
#include <hip/hip_runtime.h>

typedef __bf16 bf16x8 __attribute__((ext_vector_type(8)));
typedef float f32x4 __attribute__((ext_vector_type(4)));
typedef unsigned short u16x4 __attribute__((ext_vector_type(4)));
typedef unsigned short u16x8 __attribute__((ext_vector_type(8)));

#define MFMA16(a,b,c) __builtin_amdgcn_mfma_f32_16x16x32_bf16((a),(b),(c),0,0,0)

__device__ __forceinline__ unsigned short f2bf(float f){
  return __builtin_bit_cast(unsigned short, static_cast<__bf16>(f));
}
__device__ __forceinline__ float bf2f(unsigned short h){
  unsigned u = ((unsigned)h)<<16;
  return __builtin_bit_cast(float, u);
}
__device__ __forceinline__ bf16x8 g_frag(const unsigned short* __restrict__ wf, int fragIdx, int lane){
  return __builtin_bit_cast(bf16x8, *reinterpret_cast<const u16x8*>(wf + (size_t)(fragIdx*64 + lane)*8));
}
__device__ __forceinline__ bf16x8 lds_frag(const unsigned short* base, int fragIdx, int lane){
  return __builtin_bit_cast(bf16x8, *reinterpret_cast<const u16x8*>(base + (fragIdx*64 + lane)*8));
}
__device__ __forceinline__ bf16x8 bc(u16x8 v){ return __builtin_bit_cast(bf16x8, v); }

// Pack W^T (from W[K][M] f32 row-major) into MFMA fragment order, bf16:
// dst[((mt*KP+kp)*64+lane)*8 + j] = W[4*(lane>>4)+(j&3)+16*(j>>2)+32*kp][16*mt+(lane&15)]
// Serves as A-frag (m = row dim) or B-frag (m = col dim) -- same position map.
__device__ __forceinline__ void pack_body(const float* __restrict__ src, unsigned short* __restrict__ dst,
                                          int blk, int MT, int KP, int M){
  int tid = blk*256 + threadIdx.x;
  if (tid >= MT*KP*64) return;
  int lane = tid & 63;
  int t2 = tid >> 6;
  int kp = t2 % KP;
  int m = 16*(t2 / KP) + (lane & 15);
  int g = lane >> 4;
  u16x8 v;
#pragma unroll
  for (int j = 0; j < 8; ++j) {
    int k = 4*g + (j&3) + 16*(j>>2) + 32*kp;
    v[j] = f2bf(src[k*M + m]);
  }
  *reinterpret_cast<u16x8*>(&dst[(size_t)tid*8]) = v;
}

// One fused prep kernel: all weight packing + bias2 table. Grid = 160 blocks.
// bias2[(((h*4+mt)*4+nt)*64+lane)*4 + r2] = bias[h][key=16mt+4g+r2][q=16nt+l15]
// (replicates np.meshgrid 'xy': d/h coordinate roles swapped -- intentional)
__global__ void prep_kernel(const float* __restrict__ qkvw, const float* __restrict__ pw,
                            const float* __restrict__ w1, const float* __restrict__ w2,
                            const float* __restrict__ tbl,
                            unsigned short* __restrict__ wqk_f, unsigned short* __restrict__ wvb_f,
                            unsigned short* __restrict__ wproj_f,
                            unsigned short* __restrict__ w1_f, unsigned short* __restrict__ w2_f,
                            float* __restrict__ bias2){
  const int bb = blockIdx.x;
  if (bb < 16)      { pack_body(qkvw,       wqk_f,   bb,      16, 4, 384); return; }
  else if (bb < 24) { pack_body(qkvw + 256, wvb_f,   bb-16,    8, 4, 384); return; }
  else if (bb < 32) { pack_body(pw,         wproj_f, bb-24,    8, 4, 128); return; }
  else if (bb < 64) { pack_body(w1,         w1_f,    bb-32,   32, 4, 512); return; }
  else if (bb < 96) { pack_body(w2,         w2_f,    bb-64,    8,16, 128); return; }
  const int o = (bb-96)*256 + threadIdx.x;   // 64 blocks -> 16384 items
  int r2 = o&3, lane = (o>>2)&63, nt = (o>>8)&3, mt = (o>>10)&3, h = o>>12;
  int g = lane>>4, l15 = lane&15;
  int key = 16*mt + 4*g + r2, q = 16*nt + l15;
  int da = ((q>>2)&3) - ((key>>2)&3) + 3;
  int ha = (q>>4)     - (key>>4)     + 3;
  int wa = (q&3)      - (key&3)      + 3;
  bias2[o] = tbl[((da*7+ha)*7+wa)*4 + h];
}

__global__ __launch_bounds__(256, 3)
void swin_block_kernel(const float* __restrict__ x,
                       const float* __restrict__ n1s, const float* __restrict__ n1b,
                       const unsigned short* __restrict__ wqk,
                       const unsigned short* __restrict__ wvb,
                       const float* __restrict__ bias2,
                       const unsigned short* __restrict__ wproj,
                       const float* __restrict__ projb,
                       const float* __restrict__ n2s, const float* __restrict__ n2b,
                       const unsigned short* __restrict__ w1f, const float* __restrict__ b1,
                       const unsigned short* __restrict__ w2f, const float* __restrict__ b2,
                       float* __restrict__ out)
{
  // Two fragment-packed arenas; frag f = tile*4+kp = 64 lanes x 16B. All b128, conflict-free.
  __shared__ __align__(16) unsigned short ldsA[16*64*8];  // xn -> o -> xn2 -> mlp-stage
  __shared__ __align__(16) unsigned short ldsH[16*64*8];  // proj-stage -> mlp hidden chunks
  __shared__ int rid_s[64];

  const int tid  = threadIdx.x;
  const int lane = tid & 63;
  const int w    = tid >> 6;      // wave id = head id (attn) = channel-tile pair (proj/mlp)
  const int g    = lane >> 4;
  const int l15  = lane & 15;

  const int wb = blockIdx.x;
  const int b  = wb >> 11;
  const int r0 = wb & 2047;
  const int bd = r0 >> 8, bh = (r0 >> 4) & 15, bwi = r0 & 15;
  const bool edge = (bd==7) || (bh==15) || (bwi==15);

  // ---- phase 0: load x (roll -2 fused), LN1 -> xn frags; residual -> bf16 regs ----
  const int t = tid >> 2, qtr = tid & 3;
  const int wd = t >> 4, wh = (t >> 2) & 3, ww = t & 3;
  const int dco = (bd*4 + wd + 2) & 31;
  const int hco = (bh*4 + wh + 2) & 63;
  const int wco = (bwi*4 + ww + 2) & 63;
  const long tokl = ((long)((b*32 + dco)*64 + hco))*64 + wco;
  const float* xrow = x + tokl*128 + qtr*32;
  const int tileT = t >> 4, l15t = t & 15;

  u16x8 rsd[4];
  {
    float xr[32];
    float s = 0.f, sq = 0.f;
#pragma unroll
    for (int i = 0; i < 8; ++i) {
      float4 v = reinterpret_cast<const float4*>(xrow)[i];
      xr[4*i+0]=v.x; xr[4*i+1]=v.y; xr[4*i+2]=v.z; xr[4*i+3]=v.w;
      s  += v.x + v.y + v.z + v.w;
      sq += v.x*v.x + v.y*v.y + v.z*v.z + v.w*v.w;
    }
    s  += __shfl_xor(s, 1);  s  += __shfl_xor(s, 2);
    sq += __shfl_xor(sq, 1); sq += __shfl_xor(sq, 2);
    const float mean = s * 0.0078125f;
    const float rs   = rsqrtf(sq * 0.0078125f - mean*mean + 1e-6f);
#pragma unroll
    for (int i = 0; i < 8; ++i) {
      u16x4 o4;
#pragma unroll
      for (int j2 = 0; j2 < 4; ++j2) {
        int c = qtr*32 + 4*i + j2;
        o4[j2] = f2bf((xr[4*i+j2]-mean)*rs*n1s[c] + n1b[c]);
        rsd[i>>1][4*(i&1)+j2] = f2bf(xr[4*i+j2]);
      }
      *reinterpret_cast<u16x4*>(&ldsA[((tileT*4+qtr)*64 + l15t + 16*(i&3))*8 + 4*(i>>2)]) = o4;
    }
  }
  if (edge && tid < 64) {
    int twd = tid >> 4, twh = (tid >> 2) & 3, tww = tid & 3;
    int rd = (bd == 7)  ? (twd < 2 ? 1 : 2) : 0;
    int rh = (bh == 15) ? (twh < 2 ? 1 : 2) : 0;
    int rw = (bwi == 15)? (tww < 2 ? 1 : 2) : 0;
    rid_s[tid] = rd*9 + rh*3 + rw;
  }
  __syncthreads();   // B0: xn ready

  // ---- phase 1: QKV (wave = head); Q,K,V share the same xn frags per kp ----
  u16x8 Qf[4], Kf[4], Vf[2][2];
  {
    f32x4 qacc[2][4], kacc[2][4], vacc[4][2];
#pragma unroll
    for (int a2=0;a2<2;++a2)
#pragma unroll
      for (int b4=0;b4<4;++b4){ f32x4 z={0.f,0.f,0.f,0.f}; qacc[a2][b4]=z; kacc[a2][b4]=z; vacc[b4][a2]=z; }
#pragma unroll
    for (int kp=0;kp<4;++kp){
      bf16x8 fx[4];
#pragma unroll
      for (int nt=0;nt<4;++nt) fx[nt] = lds_frag(ldsA, nt*4+kp, lane);
#pragma unroll
      for (int mi=0;mi<2;++mi){
        bf16x8 aq = g_frag(wqk, (2*w+mi)*4+kp, lane);
#pragma unroll
        for (int nt=0;nt<4;++nt) qacc[mi][nt] = MFMA16(aq, fx[nt], qacc[mi][nt]);
      }
#pragma unroll
      for (int mi=0;mi<2;++mi){
        bf16x8 ak = g_frag(wqk, (8+2*w+mi)*4+kp, lane);
#pragma unroll
        for (int nt=0;nt<4;++nt) kacc[mi][nt] = MFMA16(ak, fx[nt], kacc[mi][nt]);
      }
#pragma unroll
      for (int c2=0;c2<2;++c2){
        bf16x8 bv = g_frag(wvb, (2*w+c2)*4+kp, lane);
#pragma unroll
        for (int mt=0;mt<4;++mt) vacc[mt][c2] = MFMA16(fx[mt], bv, vacc[mt][c2]);
      }
    }
#pragma unroll
    for (int nt=0;nt<4;++nt){
      u16x8 vq, vk;
#pragma unroll
      for (int j=0;j<8;++j){
        vq[j] = f2bf(qacc[j>>2][nt][j&3]*0.17677669529663687f);
        vk[j] = f2bf(kacc[j>>2][nt][j&3]);
      }
      Qf[nt]=vq; Kf[nt]=vk;
    }
#pragma unroll
    for (int c2=0;c2<2;++c2)
#pragma unroll
      for (int kpk=0;kpk<2;++kpk){
        u16x8 v;
#pragma unroll
        for (int j=0;j<8;++j) v[j] = f2bf(vacc[(j>>2)+2*kpk][c2][j&3]);
        Vf[c2][kpk]=v;
      }
  }
  __syncthreads();   // B1: all xn reads done (o will overwrite arena A)

  // ---- phase 2: attention in registers, streamed per q-tile ----
  {
    int4 rk[4];
    if (edge){
#pragma unroll
      for (int mt=0;mt<4;++mt) rk[mt] = *reinterpret_cast<const int4*>(&rid_s[16*mt + 4*g]);
    }
#pragma unroll
    for (int nt=0;nt<4;++nt){
      f32x4 sacc[4];
#pragma unroll
      for (int mt=0;mt<4;++mt){
        f32x4 z = {0.f,0.f,0.f,0.f};
        sacc[mt] = MFMA16(bc(Kf[mt]), bc(Qf[nt]), z);
      }
      if (edge){
        const int ridq = rid_s[16*nt + l15];
#pragma unroll
        for (int mt=0;mt<4;++mt){
          float4 bv = reinterpret_cast<const float4*>(bias2)[((w*4+mt)*4+nt)*64 + lane];
          sacc[mt][0] += bv.x + (rk[mt].x != ridq ? -100.f : 0.f);
          sacc[mt][1] += bv.y + (rk[mt].y != ridq ? -100.f : 0.f);
          sacc[mt][2] += bv.z + (rk[mt].z != ridq ? -100.f : 0.f);
          sacc[mt][3] += bv.w + (rk[mt].w != ridq ? -100.f : 0.f);
        }
      } else {
#pragma unroll
        for (int mt=0;mt<4;++mt){
          float4 bv = reinterpret_cast<const float4*>(bias2)[((w*4+mt)*4+nt)*64 + lane];
          sacc[mt][0] += bv.x; sacc[mt][1] += bv.y; sacc[mt][2] += bv.z; sacc[mt][3] += bv.w;
        }
      }
      float mx = -1e30f;
#pragma unroll
      for (int mt=0;mt<4;++mt)
#pragma unroll
        for (int r2=0;r2<4;++r2) mx = fmaxf(mx, sacc[mt][r2]);
      mx = fmaxf(mx, __shfl_xor(mx, 16));
      mx = fmaxf(mx, __shfl_xor(mx, 32));
      float sum = 0.f;
#pragma unroll
      for (int mt=0;mt<4;++mt)
#pragma unroll
        for (int r2=0;r2<4;++r2){
          float p = __expf(sacc[mt][r2] - mx);
          sacc[mt][r2] = p; sum += p;
        }
      sum += __shfl_xor(sum, 16);
      sum += __shfl_xor(sum, 32);
      const float inv = 1.f / sum;
      u16x8 Pf0, Pf1;
#pragma unroll
      for (int j=0;j<8;++j){
        Pf0[j] = f2bf(sacc[(j>>2)  ][j&3]*inv);
        Pf1[j] = f2bf(sacc[(j>>2)+2][j&3]*inv);
      }
      f32x4 oa[2];
#pragma unroll
      for (int c2=0;c2<2;++c2){
        f32x4 z = {0.f,0.f,0.f,0.f};
        z = MFMA16(bc(Vf[c2][0]), bc(Pf0), z);
        oa[c2] = MFMA16(bc(Vf[c2][1]), bc(Pf1), z);
      }
      u16x8 v;
#pragma unroll
      for (int j=0;j<8;++j) v[j] = f2bf(oa[j>>2][j&3]);
      *reinterpret_cast<u16x8*>(&ldsA[((nt*4+w)*64+lane)*8]) = v;   // frag (tok-tile nt, kp=head w)
    }
  }
  __syncthreads();   // B2: o ready

  // ---- phase 3: proj (wave = channel tiles 2w..2w+1, 4 token-tiles) -> stage ldsH ----
  {
    f32x4 pacc[2][4];
#pragma unroll
    for (int mi=0;mi<2;++mi)
#pragma unroll
      for (int nt=0;nt<4;++nt){ f32x4 z={0.f,0.f,0.f,0.f}; pacc[mi][nt]=z; }
#pragma unroll
    for (int kp=0;kp<4;++kp){
      bf16x8 bo[4];
#pragma unroll
      for (int nt=0;nt<4;++nt) bo[nt] = lds_frag(ldsA, nt*4+kp, lane);
#pragma unroll
      for (int mi=0;mi<2;++mi){
        bf16x8 a = g_frag(wproj, (2*w+mi)*4+kp, lane);
#pragma unroll
        for (int nt=0;nt<4;++nt) pacc[mi][nt] = MFMA16(a, bo[nt], pacc[mi][nt]);
      }
    }
#pragma unroll
    for (int mi=0;mi<2;++mi)
#pragma unroll
      for (int r2=0;r2<4;++r2){
        const float pb = projb[16*(2*w+mi) + 4*g + r2];
#pragma unroll
        for (int nt=0;nt<4;++nt) pacc[mi][nt][r2] += pb;
      }
#pragma unroll
    for (int nt=0;nt<4;++nt){
      u16x8 v;
#pragma unroll
      for (int j=0;j<8;++j) v[j] = f2bf(pacc[j>>2][nt][j&3]);
      *reinterpret_cast<u16x8*>(&ldsH[((nt*4+w)*64+lane)*8]) = v;
    }
  }
  __syncthreads();   // B3: proj stage ready; all o reads done

  // ---- phase 4: residual + LN2 (reads ldsH) -> xn2 frags in ldsA; resid2 -> regs ----
  {
    float xv[32];
    float s2 = 0.f, sq2 = 0.f;
#pragma unroll
    for (int i = 0; i < 8; ++i) {
      u16x4 sg = *reinterpret_cast<const u16x4*>(&ldsH[((tileT*4+qtr)*64 + l15t + 16*(i&3))*8 + 4*(i>>2)]);
#pragma unroll
      for (int j2 = 0; j2 < 4; ++j2) {
        float v2 = bf2f(rsd[i>>1][4*(i&1)+j2]) + bf2f(sg[j2]);
        xv[4*i+j2] = v2;
        s2 += v2; sq2 += v2*v2;
      }
    }
    s2  += __shfl_xor(s2, 1);  s2  += __shfl_xor(s2, 2);
    sq2 += __shfl_xor(sq2, 1); sq2 += __shfl_xor(sq2, 2);
    const float mean2 = s2*0.0078125f;
    const float rs2 = rsqrtf(sq2*0.0078125f - mean2*mean2 + 1e-6f);
#pragma unroll
    for (int i = 0; i < 8; ++i) {
      u16x4 o4;
#pragma unroll
      for (int j2 = 0; j2 < 4; ++j2) {
        int c = qtr*32 + 4*i + j2;
        o4[j2] = f2bf((xv[4*i+j2]-mean2)*rs2*n2s[c] + n2b[c]);
        rsd[i>>1][4*(i&1)+j2] = f2bf(xv[4*i+j2]);
      }
      *reinterpret_cast<u16x4*>(&ldsA[((tileT*4+qtr)*64 + l15t + 16*(i&3))*8 + 4*(i>>2)]) = o4;
    }
  }
  __syncthreads();   // B4: xn2 ready; ldsH reads done

  // ---- phase 5: MLP (wave = channel tiles), hidden in 4 chunks of 128 via ldsH ----
  {
    f32x4 macc[2][4];
#pragma unroll
    for (int mi=0;mi<2;++mi)
#pragma unroll
      for (int nt=0;nt<4;++nt){ f32x4 z={0.f,0.f,0.f,0.f}; macc[mi][nt]=z; }
#pragma unroll
    for (int cc=0;cc<4;++cc){
      f32x4 hacc[2][4];
#pragma unroll
      for (int mi=0;mi<2;++mi)
#pragma unroll
        for (int nt=0;nt<4;++nt){ f32x4 z={0.f,0.f,0.f,0.f}; hacc[mi][nt]=z; }
#pragma unroll
      for (int kp=0;kp<4;++kp){
        bf16x8 bn[4];
#pragma unroll
        for (int nt=0;nt<4;++nt) bn[nt] = lds_frag(ldsA, nt*4+kp, lane);
#pragma unroll
        for (int mi=0;mi<2;++mi){
          bf16x8 a = g_frag(w1f, (cc*8+2*w+mi)*4+kp, lane);
#pragma unroll
          for (int nt=0;nt<4;++nt) hacc[mi][nt] = MFMA16(a, bn[nt], hacc[mi][nt]);
        }
      }
#pragma unroll
      for (int nt=0;nt<4;++nt){
        u16x8 hv;
#pragma unroll
        for (int j=0;j<8;++j){
          const int mi = j>>2, r2 = j&3;
          const int hch = cc*128 + 32*w + 16*mi + 4*g + r2;
          float v2 = hacc[mi][nt][r2] + b1[hch];
          float gg = 0.7978845608028654f*(v2 + 0.044715f*v2*v2*v2);
          float ge = v2 / (1.f + __expf(-2.f*gg));   // 0.5 v (1+tanh(gg))
          hv[j] = f2bf(ge);
        }
        *reinterpret_cast<u16x8*>(&ldsH[((nt*4+w)*64+lane)*8]) = hv;
      }
      __syncthreads();   // hid chunk ready
#pragma unroll
      for (int kph=0;kph<4;++kph){
        bf16x8 bhf[4];
#pragma unroll
        for (int nt=0;nt<4;++nt) bhf[nt] = lds_frag(ldsH, nt*4+kph, lane);
#pragma unroll
        for (int mi=0;mi<2;++mi){
          bf16x8 a2 = g_frag(w2f, (2*w+mi)*16 + cc*4 + kph, lane);
#pragma unroll
          for (int nt=0;nt<4;++nt) macc[mi][nt] = MFMA16(a2, bhf[nt], macc[mi][nt]);
        }
      }
      __syncthreads();   // hid reads done (next chunk overwrites)
    }
    // mlp output (+b2) -> ldsA (xn2 dead)
#pragma unroll
    for (int nt=0;nt<4;++nt){
      u16x8 v;
#pragma unroll
      for (int j=0;j<8;++j){
        const int mi = j>>2, r2 = j&3;
        v[j] = f2bf(macc[mi][nt][r2] + b2[16*(2*w+mi) + 4*g + r2]);
      }
      *reinterpret_cast<u16x8*>(&ldsA[((nt*4+w)*64+lane)*8]) = v;
    }
  }
  __syncthreads();   // B5: mlp stage ready

  // ---- phase 6: out = resid2 + mlp (coalesced float4 stores) ----
  {
    float* orow = out + tokl*128 + qtr*32;
#pragma unroll
    for (int i = 0; i < 8; ++i) {
      u16x4 mv = *reinterpret_cast<const u16x4*>(&ldsA[((tileT*4+qtr)*64 + l15t + 16*(i&3))*8 + 4*(i>>2)]);
      float4 v;
      v.x = bf2f(rsd[i>>1][4*(i&1)+0]) + bf2f(mv[0]);
      v.y = bf2f(rsd[i>>1][4*(i&1)+1]) + bf2f(mv[1]);
      v.z = bf2f(rsd[i>>1][4*(i&1)+2]) + bf2f(mv[2]);
      v.w = bf2f(rsd[i>>1][4*(i&1)+3]) + bf2f(mv[3]);
      reinterpret_cast<float4*>(orow)[i] = v;
    }
  }
}

extern "C" void kernel_launch(void* const* d_in, const int* in_sizes, int n_in,
                              void* d_out, int out_size, void* d_ws, size_t ws_size,
                              hipStream_t stream) {
  (void)in_sizes; (void)n_in; (void)out_size; (void)ws_size;
  const float* x    = (const float*)d_in[0];
  // d_in[1] (mask) recomputed analytically in-kernel
  const float* n1s  = (const float*)d_in[2];
  const float* n1b  = (const float*)d_in[3];
  const float* qkvw = (const float*)d_in[4];
  const float* tbl  = (const float*)d_in[5];
  const float* pw   = (const float*)d_in[6];
  const float* pb   = (const float*)d_in[7];
  const float* n2s  = (const float*)d_in[8];
  const float* n2b  = (const float*)d_in[9];
  const float* w1   = (const float*)d_in[10];
  const float* b1   = (const float*)d_in[11];
  const float* w2   = (const float*)d_in[12];
  const float* b2   = (const float*)d_in[13];
  float* out = (float*)d_out;

  // ws layout (u16 units): wqk 16*4*64*8 | wvb 8*4*64*8 | wproj 8*4*64*8 | w1 32*4*64*8 | w2 8*16*64*8 | bias2 f32 16384
  unsigned short* wqk_f   = (unsigned short*)d_ws;
  unsigned short* wvb_f   = wqk_f   + 16*4*64*8;
  unsigned short* wproj_f = wvb_f   + 8*4*64*8;
  unsigned short* w1_f    = wproj_f + 8*4*64*8;
  unsigned short* w2_f    = w1_f    + 32*4*64*8;
  float*          bias2   = (float*)(w2_f + 8*16*64*8);

  prep_kernel<<<160, 256, 0, stream>>>(qkvw, pw, w1, w2, tbl,
                                       wqk_f, wvb_f, wproj_f, w1_f, w2_f, bias2);

  swin_block_kernel<<<4096, 256, 0, stream>>>(x, n1s, n1b, wqk_f, wvb_f, bias2, wproj_f, pb,
                                              n2s, n2b, w1_f, b1, w2_f, b2, out);
}

// Round 7
// 481.145 us; speedup vs baseline: 1.8014x; 1.1474x over previous
//
#include <hip/hip_runtime.h>

typedef __bf16 bf16x8 __attribute__((ext_vector_type(8)));
typedef float f32x4 __attribute__((ext_vector_type(4)));
typedef unsigned short u16x4 __attribute__((ext_vector_type(4)));
typedef unsigned short u16x8 __attribute__((ext_vector_type(8)));

#define MFMA16(a,b,c) __builtin_amdgcn_mfma_f32_16x16x32_bf16((a),(b),(c),0,0,0)

__device__ __forceinline__ unsigned short f2bf(float f){
  return __builtin_bit_cast(unsigned short, static_cast<__bf16>(f));
}
__device__ __forceinline__ float bf2f(unsigned short h){
  unsigned u = ((unsigned)h)<<16;
  return __builtin_bit_cast(float, u);
}
__device__ __forceinline__ bf16x8 g_frag(const unsigned short* __restrict__ wf, int fragIdx, int lane){
  return __builtin_bit_cast(bf16x8, *reinterpret_cast<const u16x8*>(wf + (size_t)(fragIdx*64 + lane)*8));
}
__device__ __forceinline__ bf16x8 lds_frag(const unsigned short* base, int fragIdx, int lane){
  return __builtin_bit_cast(bf16x8, *reinterpret_cast<const u16x8*>(base + (fragIdx*64 + lane)*8));
}
__device__ __forceinline__ bf16x8 bc(u16x8 v){ return __builtin_bit_cast(bf16x8, v); }

// Pack scale*W^T (from W[K][M] f32 row-major) into MFMA fragment order, bf16:
// dst[((mt*KP+kp)*64+lane)*8 + j] = scale*W[4*(lane>>4)+(j&3)+16*(j>>2)+32*kp][16*mt+(lane&15)]
// Serves as A-frag (m = row dim) or B-frag (m = col dim) -- same position map.
__device__ __forceinline__ void pack_body(const float* __restrict__ src, unsigned short* __restrict__ dst,
                                          int blk, int MT, int KP, int M, float scale){
  int tid = blk*256 + threadIdx.x;
  if (tid >= MT*KP*64) return;
  int lane = tid & 63;
  int t2 = tid >> 6;
  int kp = t2 % KP;
  int m = 16*(t2 / KP) + (lane & 15);
  int g = lane >> 4;
  u16x8 v;
#pragma unroll
  for (int j = 0; j < 8; ++j) {
    int k = 4*g + (j&3) + 16*(j>>2) + 32*kp;
    v[j] = f2bf(scale*src[k*M + m]);
  }
  *reinterpret_cast<u16x8*>(&dst[(size_t)tid*8]) = v;
}

// One fused prep kernel: all weight packing + bias2 table. Grid = 160 blocks.
// Q-tiles (bb<8) pre-scaled by hd^-0.5. bias2 layout matches attn C-fragments.
// (replicates np.meshgrid 'xy': d/h coordinate roles swapped -- intentional)
__global__ void prep_kernel(const float* __restrict__ qkvw, const float* __restrict__ pw,
                            const float* __restrict__ w1, const float* __restrict__ w2,
                            const float* __restrict__ tbl,
                            unsigned short* __restrict__ wqk_f, unsigned short* __restrict__ wvb_f,
                            unsigned short* __restrict__ wproj_f,
                            unsigned short* __restrict__ w1_f, unsigned short* __restrict__ w2_f,
                            float* __restrict__ bias2){
  const int bb = blockIdx.x;
  if (bb < 8)       { pack_body(qkvw,       wqk_f,   bb,      16, 4, 384, 0.17677669529663687f); return; }
  else if (bb < 16) { pack_body(qkvw,       wqk_f,   bb,      16, 4, 384, 1.f); return; }
  else if (bb < 24) { pack_body(qkvw + 256, wvb_f,   bb-16,    8, 4, 384, 1.f); return; }
  else if (bb < 32) { pack_body(pw,         wproj_f, bb-24,    8, 4, 128, 1.f); return; }
  else if (bb < 64) { pack_body(w1,         w1_f,    bb-32,   32, 4, 512, 1.f); return; }
  else if (bb < 96) { pack_body(w2,         w2_f,    bb-64,    8,16, 128, 1.f); return; }
  const int o = (bb-96)*256 + threadIdx.x;   // 64 blocks -> 16384 items
  int r2 = o&3, lane = (o>>2)&63, nt = (o>>8)&3, mt = (o>>10)&3, h = o>>12;
  int g = lane>>4, l15 = lane&15;
  int key = 16*mt + 4*g + r2, q = 16*nt + l15;
  int da = ((q>>2)&3) - ((key>>2)&3) + 3;
  int ha = (q>>4)     - (key>>4)     + 3;
  int wa = (q&3)      - (key&3)      + 3;
  bias2[o] = tbl[((da*7+ha)*7+wa)*4 + h];
}

__global__ __launch_bounds__(256, 2)
void swin_block_kernel(const float* __restrict__ x,
                       const float* __restrict__ n1s, const float* __restrict__ n1b,
                       const unsigned short* __restrict__ wqk,
                       const unsigned short* __restrict__ wvb,
                       const float* __restrict__ bias2,
                       const unsigned short* __restrict__ wproj,
                       const float* __restrict__ projb,
                       const float* __restrict__ n2s, const float* __restrict__ n2b,
                       const unsigned short* __restrict__ w1f, const float* __restrict__ b1,
                       const unsigned short* __restrict__ w2f, const float* __restrict__ b2,
                       float* __restrict__ out)
{
  // Two fragment-packed arenas; frag f = tile*4+kp = 64 lanes x 16B. All b128, conflict-free.
  __shared__ __align__(16) unsigned short ldsA[16*64*8];  // xn -> o -> xn2 -> mlp-stage
  __shared__ __align__(16) unsigned short ldsH[16*64*8];  // proj-stage -> mlp hidden chunks
  __shared__ int rid_s[64];

  const int tid  = threadIdx.x;
  const int lane = tid & 63;
  const int w    = tid >> 6;      // wave id = head id (attn) = channel-tile pair (proj/mlp)
  const int g    = lane >> 4;
  const int l15  = lane & 15;

  const int wb = blockIdx.x;
  const int b  = wb >> 11;
  const int r0 = wb & 2047;
  const int bd = r0 >> 8, bh = (r0 >> 4) & 15, bwi = r0 & 15;
  const bool edge = (bd==7) || (bh==15) || (bwi==15);

  // ---- phase 0: load x (roll -2 fused), LN1 -> xn frags; residual -> bf16 regs ----
  const int t = tid >> 2, qtr = tid & 3;
  const int wd = t >> 4, wh = (t >> 2) & 3, ww = t & 3;
  const int dco = (bd*4 + wd + 2) & 31;
  const int hco = (bh*4 + wh + 2) & 63;
  const int wco = (bwi*4 + ww + 2) & 63;
  const long tokl = ((long)((b*32 + dco)*64 + hco))*64 + wco;
  const float* xrow = x + tokl*128 + qtr*32;
  const int tileT = t >> 4, l15t = t & 15;

  u16x8 rsd[4];
  {
    float xr[32];
    float s = 0.f, sq = 0.f;
#pragma unroll
    for (int i = 0; i < 8; ++i) {
      float4 v = reinterpret_cast<const float4*>(xrow)[i];
      xr[4*i+0]=v.x; xr[4*i+1]=v.y; xr[4*i+2]=v.z; xr[4*i+3]=v.w;
      s  += v.x + v.y + v.z + v.w;
      sq += v.x*v.x + v.y*v.y + v.z*v.z + v.w*v.w;
    }
    s  += __shfl_xor(s, 1);  s  += __shfl_xor(s, 2);
    sq += __shfl_xor(sq, 1); sq += __shfl_xor(sq, 2);
    const float mean = s * 0.0078125f;
    const float rs   = rsqrtf(sq * 0.0078125f - mean*mean + 1e-6f);
#pragma unroll
    for (int i = 0; i < 8; ++i) {
      u16x4 o4;
#pragma unroll
      for (int j2 = 0; j2 < 4; ++j2) {
        int c = qtr*32 + 4*i + j2;
        o4[j2] = f2bf((xr[4*i+j2]-mean)*rs*n1s[c] + n1b[c]);
        rsd[i>>1][4*(i&1)+j2] = f2bf(xr[4*i+j2]);
      }
      *reinterpret_cast<u16x4*>(&ldsA[((tileT*4+qtr)*64 + l15t + 16*(i&3))*8 + 4*(i>>2)]) = o4;
    }
  }
  if (edge && tid < 64) {
    int twd = tid >> 4, twh = (tid >> 2) & 3, tww = tid & 3;
    int rd = (bd == 7)  ? (twd < 2 ? 1 : 2) : 0;
    int rh = (bh == 15) ? (twh < 2 ? 1 : 2) : 0;
    int rw = (bwi == 15)? (tww < 2 ? 1 : 2) : 0;
    rid_s[tid] = rd*9 + rh*3 + rw;
  }
  __syncthreads();   // B0: xn ready

  // ---- phase 1: QKV (wave = head), SEQUENTIAL passes to cap live accumulators ----
  u16x8 Qf[4], Kf[4], Vf[2][2];
  {
    f32x4 acc[2][4];
    // ---- Q pass (scale pre-folded into wqk tiles 0..7) ----
#pragma unroll
    for (int mi=0;mi<2;++mi)
#pragma unroll
      for (int nt=0;nt<4;++nt){ f32x4 z={0.f,0.f,0.f,0.f}; acc[mi][nt]=z; }
#pragma unroll
    for (int kp=0;kp<4;++kp){
      bf16x8 fx[4];
#pragma unroll
      for (int nt=0;nt<4;++nt) fx[nt] = lds_frag(ldsA, nt*4+kp, lane);
#pragma unroll
      for (int mi=0;mi<2;++mi){
        bf16x8 a = g_frag(wqk, (2*w+mi)*4+kp, lane);
#pragma unroll
        for (int nt=0;nt<4;++nt) acc[mi][nt] = MFMA16(a, fx[nt], acc[mi][nt]);
      }
    }
#pragma unroll
    for (int nt=0;nt<4;++nt){
      u16x8 v;
#pragma unroll
      for (int j=0;j<8;++j) v[j] = f2bf(acc[j>>2][nt][j&3]);
      Qf[nt]=v;
    }
    __builtin_amdgcn_sched_barrier(0);
    // ---- K pass ----
#pragma unroll
    for (int mi=0;mi<2;++mi)
#pragma unroll
      for (int nt=0;nt<4;++nt){ f32x4 z={0.f,0.f,0.f,0.f}; acc[mi][nt]=z; }
#pragma unroll
    for (int kp=0;kp<4;++kp){
      bf16x8 fx[4];
#pragma unroll
      for (int nt=0;nt<4;++nt) fx[nt] = lds_frag(ldsA, nt*4+kp, lane);
#pragma unroll
      for (int mi=0;mi<2;++mi){
        bf16x8 a = g_frag(wqk, (8+2*w+mi)*4+kp, lane);
#pragma unroll
        for (int nt=0;nt<4;++nt) acc[mi][nt] = MFMA16(a, fx[nt], acc[mi][nt]);
      }
    }
#pragma unroll
    for (int nt=0;nt<4;++nt){
      u16x8 v;
#pragma unroll
      for (int j=0;j<8;++j) v[j] = f2bf(acc[j>>2][nt][j&3]);
      Kf[nt]=v;
    }
    __builtin_amdgcn_sched_barrier(0);
    // ---- V pass: V = xn . Wv^T -> V[tok][ch] ----
    f32x4 vacc[4][2];
#pragma unroll
    for (int mt=0;mt<4;++mt)
#pragma unroll
      for (int c2=0;c2<2;++c2){ f32x4 z={0.f,0.f,0.f,0.f}; vacc[mt][c2]=z; }
#pragma unroll
    for (int kp=0;kp<4;++kp){
      bf16x8 fx[4];
#pragma unroll
      for (int mt=0;mt<4;++mt) fx[mt] = lds_frag(ldsA, mt*4+kp, lane);
#pragma unroll
      for (int c2=0;c2<2;++c2){
        bf16x8 bv = g_frag(wvb, (2*w+c2)*4+kp, lane);
#pragma unroll
        for (int mt=0;mt<4;++mt) vacc[mt][c2] = MFMA16(fx[mt], bv, vacc[mt][c2]);
      }
    }
#pragma unroll
    for (int c2=0;c2<2;++c2)
#pragma unroll
      for (int kpk=0;kpk<2;++kpk){
        u16x8 v;
#pragma unroll
        for (int j=0;j<8;++j) v[j] = f2bf(vacc[(j>>2)+2*kpk][c2][j&3]);
        Vf[c2][kpk]=v;
      }
    __builtin_amdgcn_sched_barrier(0);
  }
  __syncthreads();   // B1: all xn reads done (o will overwrite arena A)

  // ---- phase 2: attention in registers, streamed per q-tile ----
  {
    int4 rk[4];
    if (edge){
#pragma unroll
      for (int mt=0;mt<4;++mt) rk[mt] = *reinterpret_cast<const int4*>(&rid_s[16*mt + 4*g]);
    }
#pragma unroll
    for (int nt=0;nt<4;++nt){
      f32x4 sacc[4];
#pragma unroll
      for (int mt=0;mt<4;++mt){
        f32x4 z = {0.f,0.f,0.f,0.f};
        sacc[mt] = MFMA16(bc(Kf[mt]), bc(Qf[nt]), z);
      }
      if (edge){
        const int ridq = rid_s[16*nt + l15];
#pragma unroll
        for (int mt=0;mt<4;++mt){
          float4 bv = reinterpret_cast<const float4*>(bias2)[((w*4+mt)*4+nt)*64 + lane];
          sacc[mt][0] += bv.x + (rk[mt].x != ridq ? -100.f : 0.f);
          sacc[mt][1] += bv.y + (rk[mt].y != ridq ? -100.f : 0.f);
          sacc[mt][2] += bv.z + (rk[mt].z != ridq ? -100.f : 0.f);
          sacc[mt][3] += bv.w + (rk[mt].w != ridq ? -100.f : 0.f);
        }
      } else {
#pragma unroll
        for (int mt=0;mt<4;++mt){
          float4 bv = reinterpret_cast<const float4*>(bias2)[((w*4+mt)*4+nt)*64 + lane];
          sacc[mt][0] += bv.x; sacc[mt][1] += bv.y; sacc[mt][2] += bv.z; sacc[mt][3] += bv.w;
        }
      }
      float mx = -1e30f;
#pragma unroll
      for (int mt=0;mt<4;++mt)
#pragma unroll
        for (int r2=0;r2<4;++r2) mx = fmaxf(mx, sacc[mt][r2]);
      mx = fmaxf(mx, __shfl_xor(mx, 16));
      mx = fmaxf(mx, __shfl_xor(mx, 32));
      float sum = 0.f;
#pragma unroll
      for (int mt=0;mt<4;++mt)
#pragma unroll
        for (int r2=0;r2<4;++r2){
          float p = __expf(sacc[mt][r2] - mx);
          sacc[mt][r2] = p; sum += p;
        }
      sum += __shfl_xor(sum, 16);
      sum += __shfl_xor(sum, 32);
      const float inv = 1.f / sum;
      u16x8 Pf0, Pf1;
#pragma unroll
      for (int j=0;j<8;++j){
        Pf0[j] = f2bf(sacc[(j>>2)  ][j&3]*inv);
        Pf1[j] = f2bf(sacc[(j>>2)+2][j&3]*inv);
      }
      f32x4 oa[2];
#pragma unroll
      for (int c2=0;c2<2;++c2){
        f32x4 z = {0.f,0.f,0.f,0.f};
        z = MFMA16(bc(Vf[c2][0]), bc(Pf0), z);
        oa[c2] = MFMA16(bc(Vf[c2][1]), bc(Pf1), z);
      }
      u16x8 v;
#pragma unroll
      for (int j=0;j<8;++j) v[j] = f2bf(oa[j>>2][j&3]);
      *reinterpret_cast<u16x8*>(&ldsA[((nt*4+w)*64+lane)*8]) = v;   // frag (tok-tile nt, kp=head w)
    }
  }
  __syncthreads();   // B2: o ready

  // ---- phase 3: proj (wave = channel tiles 2w..2w+1, 4 token-tiles) -> stage ldsH ----
  {
    f32x4 pacc[2][4];
#pragma unroll
    for (int mi=0;mi<2;++mi)
#pragma unroll
      for (int nt=0;nt<4;++nt){ f32x4 z={0.f,0.f,0.f,0.f}; pacc[mi][nt]=z; }
#pragma unroll
    for (int kp=0;kp<4;++kp){
      bf16x8 bo[4];
#pragma unroll
      for (int nt=0;nt<4;++nt) bo[nt] = lds_frag(ldsA, nt*4+kp, lane);
#pragma unroll
      for (int mi=0;mi<2;++mi){
        bf16x8 a = g_frag(wproj, (2*w+mi)*4+kp, lane);
#pragma unroll
        for (int nt=0;nt<4;++nt) pacc[mi][nt] = MFMA16(a, bo[nt], pacc[mi][nt]);
      }
    }
#pragma unroll
    for (int mi=0;mi<2;++mi)
#pragma unroll
      for (int r2=0;r2<4;++r2){
        const float pb = projb[16*(2*w+mi) + 4*g + r2];
#pragma unroll
        for (int nt=0;nt<4;++nt) pacc[mi][nt][r2] += pb;
      }
#pragma unroll
    for (int nt=0;nt<4;++nt){
      u16x8 v;
#pragma unroll
      for (int j=0;j<8;++j) v[j] = f2bf(pacc[j>>2][nt][j&3]);
      *reinterpret_cast<u16x8*>(&ldsH[((nt*4+w)*64+lane)*8]) = v;
    }
  }
  __syncthreads();   // B3: proj stage ready; all o reads done

  // ---- phase 4: residual + LN2 (reads ldsH) -> xn2 frags in ldsA; resid2 -> regs ----
  {
    float xv[32];
    float s2 = 0.f, sq2 = 0.f;
#pragma unroll
    for (int i = 0; i < 8; ++i) {
      u16x4 sg = *reinterpret_cast<const u16x4*>(&ldsH[((tileT*4+qtr)*64 + l15t + 16*(i&3))*8 + 4*(i>>2)]);
#pragma unroll
      for (int j2 = 0; j2 < 4; ++j2) {
        float v2 = bf2f(rsd[i>>1][4*(i&1)+j2]) + bf2f(sg[j2]);
        xv[4*i+j2] = v2;
        s2 += v2; sq2 += v2*v2;
      }
    }
    s2  += __shfl_xor(s2, 1);  s2  += __shfl_xor(s2, 2);
    sq2 += __shfl_xor(sq2, 1); sq2 += __shfl_xor(sq2, 2);
    const float mean2 = s2*0.0078125f;
    const float rs2 = rsqrtf(sq2*0.0078125f - mean2*mean2 + 1e-6f);
#pragma unroll
    for (int i = 0; i < 8; ++i) {
      u16x4 o4;
#pragma unroll
      for (int j2 = 0; j2 < 4; ++j2) {
        int c = qtr*32 + 4*i + j2;
        o4[j2] = f2bf((xv[4*i+j2]-mean2)*rs2*n2s[c] + n2b[c]);
        rsd[i>>1][4*(i&1)+j2] = f2bf(xv[4*i+j2]);
      }
      *reinterpret_cast<u16x4*>(&ldsA[((tileT*4+qtr)*64 + l15t + 16*(i&3))*8 + 4*(i>>2)]) = o4;
    }
  }
  __syncthreads();   // B4: xn2 ready; ldsH reads done

  // ---- phase 5: MLP (wave = channel tiles), hidden in 4 chunks of 128 via ldsH ----
  {
    f32x4 macc[2][4];
#pragma unroll
    for (int mi=0;mi<2;++mi)
#pragma unroll
      for (int nt=0;nt<4;++nt){ f32x4 z={0.f,0.f,0.f,0.f}; macc[mi][nt]=z; }
#pragma unroll
    for (int cc=0;cc<4;++cc){
      f32x4 hacc[2][4];
#pragma unroll
      for (int mi=0;mi<2;++mi)
#pragma unroll
        for (int nt=0;nt<4;++nt){ f32x4 z={0.f,0.f,0.f,0.f}; hacc[mi][nt]=z; }
#pragma unroll
      for (int kp=0;kp<4;++kp){
        bf16x8 bn[4];
#pragma unroll
        for (int nt=0;nt<4;++nt) bn[nt] = lds_frag(ldsA, nt*4+kp, lane);
#pragma unroll
        for (int mi=0;mi<2;++mi){
          bf16x8 a = g_frag(w1f, (cc*8+2*w+mi)*4+kp, lane);
#pragma unroll
          for (int nt=0;nt<4;++nt) hacc[mi][nt] = MFMA16(a, bn[nt], hacc[mi][nt]);
        }
      }
#pragma unroll
      for (int nt=0;nt<4;++nt){
        u16x8 hv;
#pragma unroll
        for (int j=0;j<8;++j){
          const int mi = j>>2, r2 = j&3;
          const int hch = cc*128 + 32*w + 16*mi + 4*g + r2;
          float v2 = hacc[mi][nt][r2] + b1[hch];
          float gg = 0.7978845608028654f*(v2 + 0.044715f*v2*v2*v2);
          float ge = v2 / (1.f + __expf(-2.f*gg));   // 0.5 v (1+tanh(gg))
          hv[j] = f2bf(ge);
        }
        *reinterpret_cast<u16x8*>(&ldsH[((nt*4+w)*64+lane)*8]) = hv;
      }
      __syncthreads();   // hid chunk ready
#pragma unroll
      for (int kph=0;kph<4;++kph){
        bf16x8 bhf[4];
#pragma unroll
        for (int nt=0;nt<4;++nt) bhf[nt] = lds_frag(ldsH, nt*4+kph, lane);
#pragma unroll
        for (int mi=0;mi<2;++mi){
          bf16x8 a2 = g_frag(w2f, (2*w+mi)*16 + cc*4 + kph, lane);
#pragma unroll
          for (int nt=0;nt<4;++nt) macc[mi][nt] = MFMA16(a2, bhf[nt], macc[mi][nt]);
        }
      }
      __syncthreads();   // hid reads done (next chunk overwrites)
    }
    // mlp output (+b2) -> ldsA (xn2 dead)
#pragma unroll
    for (int nt=0;nt<4;++nt){
      u16x8 v;
#pragma unroll
      for (int j=0;j<8;++j){
        const int mi = j>>2, r2 = j&3;
        v[j] = f2bf(macc[mi][nt][r2] + b2[16*(2*w+mi) + 4*g + r2]);
      }
      *reinterpret_cast<u16x8*>(&ldsA[((nt*4+w)*64+lane)*8]) = v;
    }
  }
  __syncthreads();   // B5: mlp stage ready

  // ---- phase 6: out = resid2 + mlp (coalesced float4 stores) ----
  {
    float* orow = out + tokl*128 + qtr*32;
#pragma unroll
    for (int i = 0; i < 8; ++i) {
      u16x4 mv = *reinterpret_cast<const u16x4*>(&ldsA[((tileT*4+qtr)*64 + l15t + 16*(i&3))*8 + 4*(i>>2)]);
      float4 v;
      v.x = bf2f(rsd[i>>1][4*(i&1)+0]) + bf2f(mv[0]);
      v.y = bf2f(rsd[i>>1][4*(i&1)+1]) + bf2f(mv[1]);
      v.z = bf2f(rsd[i>>1][4*(i&1)+2]) + bf2f(mv[2]);
      v.w = bf2f(rsd[i>>1][4*(i&1)+3]) + bf2f(mv[3]);
      reinterpret_cast<float4*>(orow)[i] = v;
    }
  }
}

extern "C" void kernel_launch(void* const* d_in, const int* in_sizes, int n_in,
                              void* d_out, int out_size, void* d_ws, size_t ws_size,
                              hipStream_t stream) {
  (void)in_sizes; (void)n_in; (void)out_size; (void)ws_size;
  const float* x    = (const float*)d_in[0];
  // d_in[1] (mask) recomputed analytically in-kernel
  const float* n1s  = (const float*)d_in[2];
  const float* n1b  = (const float*)d_in[3];
  const float* qkvw = (const float*)d_in[4];
  const float* tbl  = (const float*)d_in[5];
  const float* pw   = (const float*)d_in[6];
  const float* pb   = (const float*)d_in[7];
  const float* n2s  = (const float*)d_in[8];
  const float* n2b  = (const float*)d_in[9];
  const float* w1   = (const float*)d_in[10];
  const float* b1   = (const float*)d_in[11];
  const float* w2   = (const float*)d_in[12];
  const float* b2   = (const float*)d_in[13];
  float* out = (float*)d_out;

  // ws layout (u16 units): wqk 16*4*64*8 | wvb 8*4*64*8 | wproj 8*4*64*8 | w1 32*4*64*8 | w2 8*16*64*8 | bias2 f32 16384
  unsigned short* wqk_f   = (unsigned short*)d_ws;
  unsigned short* wvb_f   = wqk_f   + 16*4*64*8;
  unsigned short* wproj_f = wvb_f   + 8*4*64*8;
  unsigned short* w1_f    = wproj_f + 8*4*64*8;
  unsigned short* w2_f    = w1_f    + 32*4*64*8;
  float*          bias2   = (float*)(w2_f + 8*16*64*8);

  prep_kernel<<<160, 256, 0, stream>>>(qkvw, pw, w1, w2, tbl,
                                       wqk_f, wvb_f, wproj_f, w1_f, w2_f, bias2);

  swin_block_kernel<<<4096, 256, 0, stream>>>(x, n1s, n1b, wqk_f, wvb_f, bias2, wproj_f, pb,
                                              n2s, n2b, w1_f, b1, w2_f, b2, out);
}